// Round 3
// baseline (943.117 us; speedup 1.0000x reference)
//
#include <hip/hip_runtime.h>
#include <hip/hip_bf16.h>
#include <stdint.h>

// Problem constants (from reference)
#define N_NODES 100000
#define N_EDGES 1600000
#define NFEAT   256
#define NHID    128
#define NEG_SLOPE 0.2f
#define GM 16   // nodes per GEMM block (100000 / 16 = 6250 exactly)

__device__ __forceinline__ int clamp_node(int v) {
    unsigned u = (unsigned)v;
    return (u < (unsigned)N_NODES) ? (int)u : 0;
}

// ---------------------------------------------------------------------------
// K1: h = x @ W (fp32). Block = 256 threads = 16 nodes.
// Thread t: col c = t&127, node strip g = t>>7 (8 nodes each).
// x loads are wave-uniform float4 (L1 broadcast); W rows are coalesced and
// L2-resident (128 KB).
// ---------------------------------------------------------------------------
__global__ __launch_bounds__(256) void k_gemm(
    const float* __restrict__ x,   // [N, 256]
    const float* __restrict__ W,   // [256, 128]
    float* __restrict__ h)         // [N, 128]
{
    const int t = threadIdx.x;
    const int c = t & 127;
    const int g = t >> 7;                       // 0 or 1
    const int nb = blockIdx.x * GM + g * 8;     // first node of this strip

    float acc[8] = {0.f, 0.f, 0.f, 0.f, 0.f, 0.f, 0.f, 0.f};
    const float* xb = x + (size_t)nb * NFEAT;

    for (int k0 = 0; k0 < NFEAT; k0 += 4) {
        float w0 = W[(k0 + 0) * NHID + c];
        float w1 = W[(k0 + 1) * NHID + c];
        float w2 = W[(k0 + 2) * NHID + c];
        float w3 = W[(k0 + 3) * NHID + c];
#pragma unroll
        for (int m = 0; m < 8; ++m) {
            float4 xv = *(const float4*)(xb + (size_t)m * NFEAT + k0);
            acc[m] += xv.x * w0;
            acc[m] += xv.y * w1;
            acc[m] += xv.z * w2;
            acc[m] += xv.w * w3;
        }
    }
#pragma unroll
    for (int m = 0; m < 8; ++m)
        h[(size_t)(nb + m) * NHID + c] = acc[m];
}

// ---------------------------------------------------------------------------
// K2: attention scalars a_src[i] = h[i]·att_src, a_dst[i] = h[i]·att_dst.
// One wave per node.
// ---------------------------------------------------------------------------
__global__ __launch_bounds__(256) void k_att(
    const float* __restrict__ h,
    const float* __restrict__ atts,  // [128]
    const float* __restrict__ attd,  // [128]
    float* __restrict__ asrc,
    float* __restrict__ adst)
{
    const int wave = threadIdx.x >> 6;
    const int lane = threadIdx.x & 63;
    const int i = blockIdx.x * 4 + wave;
    if (i >= N_NODES) return;

    float2 hv = ((const float2*)(h + (size_t)i * NHID))[lane];
    float ps = hv.x * atts[2 * lane] + hv.y * atts[2 * lane + 1];
    float pd = hv.x * attd[2 * lane] + hv.y * attd[2 * lane + 1];
#pragma unroll
    for (int off = 32; off > 0; off >>= 1) {
        ps += __shfl_down(ps, off);
        pd += __shfl_down(pd, off);
    }
    if (lane == 0) {
        asrc[i] = ps;
        adst[i] = pd;
    }
}

// ---------------------------------------------------------------------------
// CSR build (scan-free): histogram -> atomic segment allocation -> scatter.
// Segment order across nodes is irrelevant.
// ---------------------------------------------------------------------------
__global__ void k_hist(const int* __restrict__ ei, int* __restrict__ cnt)
{
    int e = blockIdx.x * blockDim.x + threadIdx.x;
    if (e < N_EDGES) atomicAdd(&cnt[clamp_node(ei[N_EDGES + e])], 1);
}

__global__ void k_alloc(const int* __restrict__ cnt, int* __restrict__ offs,
                        int* __restrict__ total)
{
    int i = blockIdx.x * blockDim.x + threadIdx.x;
    if (i < N_NODES) offs[i] = atomicAdd(total, cnt[i]);
}

__global__ void k_scatter(const int* __restrict__ ei, const int* __restrict__ offs,
                          int* __restrict__ cursor, int* __restrict__ esrc)
{
    int e = blockIdx.x * blockDim.x + threadIdx.x;
    if (e < N_EDGES) {
        int d = clamp_node(ei[N_EDGES + e]);
        int s = clamp_node(ei[e]);
        int pos = offs[d] + atomicAdd(&cursor[d], 1);
        if ((unsigned)pos < (unsigned)N_EDGES) esrc[pos] = s;
    }
}

// ---------------------------------------------------------------------------
// K3: per-node softmax-weighted aggregation + fused FC + log_softmax.
// One wave per node; lane holds feature cols {2*lane, 2*lane+1}.
// Unnormalized accumulation (|e| is O(1); exp clamped for safety).
// ---------------------------------------------------------------------------
__global__ __launch_bounds__(256) void k_agg(
    const float* __restrict__ h, const float* __restrict__ asrc,
    const float* __restrict__ adst, const int* __restrict__ offs,
    const int* __restrict__ cnt, const int* __restrict__ esrc,
    const float* __restrict__ bias,  // [128]
    const float* __restrict__ fcw,   // [2,128]
    const float* __restrict__ fcb,   // [2]
    float* __restrict__ out)         // [N,2]
{
    const int wave = threadIdx.x >> 6;
    const int lane = threadIdx.x & 63;
    const int i = blockIdx.x * 4 + wave;
    if (i >= N_NODES) return;

    const float adi = adst[i];
    // self loop (reference appends one per node)
    float e0 = asrc[i] + adi;
    e0 = (e0 > 0.f) ? e0 : NEG_SLOPE * e0;
    float w = __expf(fminf(e0, 60.f));
    float2 hv = ((const float2*)(h + (size_t)i * NHID))[lane];
    float accx = w * hv.x, accy = w * hv.y, ssum = w;

    const int jb = offs[i];
    const int je = jb + cnt[i];
    for (int j = jb; j < je; ++j) {
        int sv = esrc[j];
        float a = asrc[sv] + adi;
        a = (a > 0.f) ? a : NEG_SLOPE * a;
        float ww = __expf(fminf(a, 60.f));
        float2 hs = ((const float2*)(h + (size_t)sv * NHID))[lane];
        accx += ww * hs.x;
        accy += ww * hs.y;
        ssum += ww;
    }

    float inv = 1.0f / (ssum + 1e-16f);
    float ox = accx * inv + bias[2 * lane];
    float oy = accy * inv + bias[2 * lane + 1];

    // fused classifier: logits = out · fc_w^T + fc_b, then log_softmax
    float l0 = ox * fcw[2 * lane] + oy * fcw[2 * lane + 1];
    float l1 = ox * fcw[NHID + 2 * lane] + oy * fcw[NHID + 2 * lane + 1];
#pragma unroll
    for (int off = 32; off > 0; off >>= 1) {
        l0 += __shfl_down(l0, off);
        l1 += __shfl_down(l1, off);
    }
    if (lane == 0) {
        l0 += fcb[0];
        l1 += fcb[1];
        float m = fmaxf(l0, l1);
        float ls = m + __logf(__expf(l0 - m) + __expf(l1 - m));
        ((float2*)out)[i] = make_float2(l0 - ls, l1 - ls);
    }
}

// ---------------------------------------------------------------------------
extern "C" void kernel_launch(void* const* d_in, const int* in_sizes, int n_in,
                              void* d_out, int out_size, void* d_ws, size_t ws_size,
                              hipStream_t stream)
{
    const float* x    = (const float*)d_in[0];  // f32 [100000,256]
    const int*   ei   = (const int*)d_in[1];    // int32 [2,1600000]
    const float* W    = (const float*)d_in[2];  // f32 [256,128]
    const float* atts = (const float*)d_in[3];  // f32 [128]
    const float* attd = (const float*)d_in[4];  // f32 [128]
    const float* bias = (const float*)d_in[5];  // f32 [128]
    const float* fcw  = (const float*)d_in[6];  // f32 [2,128]
    const float* fcb  = (const float*)d_in[7];  // f32 [2]
    float*       out  = (float*)d_out;          // f32 [100000,2]

    char* base = (char*)d_ws;
    size_t off = 0;
    auto carve = [&](size_t bytes) -> char* {
        char* p = base + off;
        off = (off + bytes + 255) & ~(size_t)255;
        return p;
    };
    float* h      = (float*)carve((size_t)N_NODES * NHID * 4);  // 51.2 MB
    float* asrc   = (float*)carve(N_NODES * 4);
    float* adst   = (float*)carve(N_NODES * 4);
    int*   cnt    = (int*)carve(N_NODES * 4);
    int*   offs   = (int*)carve(N_NODES * 4);
    int*   cursor = (int*)carve(N_NODES * 4);
    int*   total  = (int*)carve(256);
    int*   esrc   = (int*)carve((size_t)N_EDGES * 4);
    (void)ws_size; (void)in_sizes; (void)n_in; (void)out_size;

    hipMemsetAsync(cnt, 0, N_NODES * 4, stream);
    hipMemsetAsync(cursor, 0, N_NODES * 4, stream);
    hipMemsetAsync(total, 0, 4, stream);

    k_gemm<<<N_NODES / GM, 256, 0, stream>>>(x, W, h);
    k_att<<<(N_NODES + 3) / 4, 256, 0, stream>>>(h, atts, attd, asrc, adst);
    k_hist<<<(N_EDGES + 255) / 256, 256, 0, stream>>>(ei, cnt);
    k_alloc<<<(N_NODES + 255) / 256, 256, 0, stream>>>(cnt, offs, total);
    k_scatter<<<(N_EDGES + 255) / 256, 256, 0, stream>>>(ei, offs, cursor, esrc);
    k_agg<<<(N_NODES + 3) / 4, 256, 0, stream>>>(h, asrc, adst, offs, cnt, esrc,
                                                 bias, fcw, fcb, out);
}

// Round 4
// 554.759 us; speedup vs baseline: 1.7000x; 1.7000x over previous
//
#include <hip/hip_runtime.h>
#include <hip/hip_bf16.h>
#include <stdint.h>

// Problem constants (from reference)
#define N_NODES 100000
#define N_EDGES 1600000
#define NFEAT   256
#define NHID    128
#define NEG_SLOPE 0.2f

typedef __attribute__((ext_vector_type(8))) short short8;   // 8 bf16 (4 VGPRs)
typedef __attribute__((ext_vector_type(4))) float f32x4;    // MFMA C/D frag

__device__ __forceinline__ int clamp_node(int v) {
    unsigned u = (unsigned)v;
    return (u < (unsigned)N_NODES) ? (int)u : 0;
}

// fp32 -> bf16 (RNE). Exact when the fp32 value is already bf16-rounded.
__device__ __forceinline__ unsigned short f2bf(float f) {
    unsigned u = __float_as_uint(f);
    return (unsigned short)((u + 0x7fffu + ((u >> 16) & 1u)) >> 16);
}

// ---------------------------------------------------------------------------
// K0: W [256,128] fp32 -> Wt [128,256] bf16 (n-major, so B-tile staging reads
// contiguous k-runs per output column).
// ---------------------------------------------------------------------------
__global__ __launch_bounds__(256) void k_conv(
    const float* __restrict__ W, unsigned short* __restrict__ Wt)
{
    int id = blockIdx.x * 256 + threadIdx.x;  // 0 .. 32767 = n*256 + k
    int n = id >> 8, k = id & 255;
    Wt[id] = f2bf(W[k * NHID + n]);
}

// ---------------------------------------------------------------------------
// K1: h = x @ W via bf16 MFMA, fp32 accumulate. Block = 256 thr = 4 waves,
// 128x128 output tile (wave grid 2x2, each wave 64x64 = 4x4 16x16 tiles).
// K-loop: 8 iters of BK=32. A (x) converted fp32->bf16 during LDS staging.
// LDS rows padded to 40 bf16 (80 B) to keep ds_read_b128 16B-aligned.
// Fragment layouts (HW-verified, guide §3): A[m=lane&15][k=quad*8+j],
// B[k=quad*8+j][n=lane&15], C/D col=lane&15, row=quad*4+reg.
// ---------------------------------------------------------------------------
#define LDS_STRIDE 40
__global__ __launch_bounds__(256) void k_gemm_mfma(
    const float* __restrict__ x,            // [N, 256] fp32 (bf16-valued)
    const unsigned short* __restrict__ Wt,  // [128, 256] bf16, n-major
    float* __restrict__ h)                  // [N, 128] fp32
{
    __shared__ unsigned short As[128 * LDS_STRIDE];
    __shared__ unsigned short Bs[128 * LDS_STRIDE];

    const int tid  = threadIdx.x;
    const int wave = tid >> 6;
    const int lane = tid & 63;
    const int wm = wave >> 1, wn = wave & 1;
    const int lr = lane & 15, q = lane >> 4;
    const int blockM = blockIdx.x * 128;

    const int sr = tid >> 1;   // staging row 0..127
    const int hh = tid & 1;    // staging half (16 elems each)

    f32x4 acc[4][4];
#pragma unroll
    for (int a = 0; a < 4; ++a)
#pragma unroll
        for (int b = 0; b < 4; ++b) acc[a][b] = 0.f;

    const int growA = min(blockM + sr, N_NODES - 1);  // clamp partial last block
    const float* xrow = x + (size_t)growA * NFEAT + hh * 16;
    const unsigned short* wrow = Wt + sr * NFEAT + hh * 16;

    for (int kt = 0; kt < 8; ++kt) {
        // ---- fetch (no LDS deps): A 16 fp32 -> 16 bf16; B 16 bf16 raw ----
        const float4* xp = (const float4*)(xrow + kt * 32);
        float4 v0 = xp[0], v1 = xp[1], v2 = xp[2], v3 = xp[3];
        short8 pa0, pa1;
        pa0[0] = f2bf(v0.x); pa0[1] = f2bf(v0.y); pa0[2] = f2bf(v0.z); pa0[3] = f2bf(v0.w);
        pa0[4] = f2bf(v1.x); pa0[5] = f2bf(v1.y); pa0[6] = f2bf(v1.z); pa0[7] = f2bf(v1.w);
        pa1[0] = f2bf(v2.x); pa1[1] = f2bf(v2.y); pa1[2] = f2bf(v2.z); pa1[3] = f2bf(v2.w);
        pa1[4] = f2bf(v3.x); pa1[5] = f2bf(v3.y); pa1[6] = f2bf(v3.z); pa1[7] = f2bf(v3.w);
        uint4 pb0 = *(const uint4*)(wrow + kt * 32);
        uint4 pb1 = *(const uint4*)(wrow + kt * 32 + 8);

        __syncthreads();  // WAR: previous iter's frag reads done
        *(short8*)&As[sr * LDS_STRIDE + hh * 16 + 0] = pa0;
        *(short8*)&As[sr * LDS_STRIDE + hh * 16 + 8] = pa1;
        *(uint4*)&Bs[sr * LDS_STRIDE + hh * 16 + 0] = pb0;
        *(uint4*)&Bs[sr * LDS_STRIDE + hh * 16 + 8] = pb1;
        __syncthreads();  // RAW: writes visible

        short8 af[4], bf[4];
#pragma unroll
        for (int mt = 0; mt < 4; ++mt)
            af[mt] = *(const short8*)&As[(wm * 64 + mt * 16 + lr) * LDS_STRIDE + q * 8];
#pragma unroll
        for (int nt = 0; nt < 4; ++nt)
            bf[nt] = *(const short8*)&Bs[(wn * 64 + nt * 16 + lr) * LDS_STRIDE + q * 8];

#pragma unroll
        for (int mt = 0; mt < 4; ++mt)
#pragma unroll
            for (int nt = 0; nt < 4; ++nt)
                acc[mt][nt] = __builtin_amdgcn_mfma_f32_16x16x32_bf16(
                    af[mt], bf[nt], acc[mt][nt], 0, 0, 0);
    }

    // epilogue: C/D layout col=lane&15, row=quad*4+reg
#pragma unroll
    for (int mt = 0; mt < 4; ++mt) {
#pragma unroll
        for (int reg = 0; reg < 4; ++reg) {
            int grow = blockM + wm * 64 + mt * 16 + q * 4 + reg;
            if (grow < N_NODES) {
                float* hp = h + (size_t)grow * NHID + wn * 64 + lr;
#pragma unroll
                for (int nt = 0; nt < 4; ++nt)
                    hp[nt * 16] = acc[mt][nt][reg];
            }
        }
    }
}

// ---------------------------------------------------------------------------
// K2: attention scalars a_src[i] = h[i]·att_src, a_dst[i] = h[i]·att_dst.
// One wave per node.
// ---------------------------------------------------------------------------
__global__ __launch_bounds__(256) void k_att(
    const float* __restrict__ h,
    const float* __restrict__ atts,  // [128]
    const float* __restrict__ attd,  // [128]
    float* __restrict__ asrc,
    float* __restrict__ adst)
{
    const int wave = threadIdx.x >> 6;
    const int lane = threadIdx.x & 63;
    const int i = blockIdx.x * 4 + wave;
    if (i >= N_NODES) return;

    float2 hv = ((const float2*)(h + (size_t)i * NHID))[lane];
    float ps = hv.x * atts[2 * lane] + hv.y * atts[2 * lane + 1];
    float pd = hv.x * attd[2 * lane] + hv.y * attd[2 * lane + 1];
#pragma unroll
    for (int off = 32; off > 0; off >>= 1) {
        ps += __shfl_down(ps, off);
        pd += __shfl_down(pd, off);
    }
    if (lane == 0) {
        asrc[i] = ps;
        adst[i] = pd;
    }
}

// ---------------------------------------------------------------------------
// CSR build (scan-free): histogram -> atomic segment allocation -> scatter.
// ---------------------------------------------------------------------------
__global__ void k_hist(const int* __restrict__ ei, int* __restrict__ cnt)
{
    int e = blockIdx.x * blockDim.x + threadIdx.x;
    if (e < N_EDGES) atomicAdd(&cnt[clamp_node(ei[N_EDGES + e])], 1);
}

__global__ void k_alloc(const int* __restrict__ cnt, int* __restrict__ offs,
                        int* __restrict__ total)
{
    int i = blockIdx.x * blockDim.x + threadIdx.x;
    if (i < N_NODES) offs[i] = atomicAdd(total, cnt[i]);
}

__global__ void k_scatter(const int* __restrict__ ei, const int* __restrict__ offs,
                          int* __restrict__ cursor, int* __restrict__ esrc)
{
    int e = blockIdx.x * blockDim.x + threadIdx.x;
    if (e < N_EDGES) {
        int d = clamp_node(ei[N_EDGES + e]);
        int s = clamp_node(ei[e]);
        int pos = offs[d] + atomicAdd(&cursor[d], 1);
        if ((unsigned)pos < (unsigned)N_EDGES) esrc[pos] = s;
    }
}

// ---------------------------------------------------------------------------
// K3: per-node softmax-weighted aggregation + fused FC + log_softmax.
// One wave per node; lane holds feature cols {2*lane, 2*lane+1}.
// ---------------------------------------------------------------------------
__global__ __launch_bounds__(256) void k_agg(
    const float* __restrict__ h, const float* __restrict__ asrc,
    const float* __restrict__ adst, const int* __restrict__ offs,
    const int* __restrict__ cnt, const int* __restrict__ esrc,
    const float* __restrict__ bias,  // [128]
    const float* __restrict__ fcw,   // [2,128]
    const float* __restrict__ fcb,   // [2]
    float* __restrict__ out)         // [N,2]
{
    const int wave = threadIdx.x >> 6;
    const int lane = threadIdx.x & 63;
    const int i = blockIdx.x * 4 + wave;
    if (i >= N_NODES) return;

    const float adi = adst[i];
    float e0 = asrc[i] + adi;                 // self loop
    e0 = (e0 > 0.f) ? e0 : NEG_SLOPE * e0;
    float w = __expf(fminf(e0, 60.f));
    float2 hv = ((const float2*)(h + (size_t)i * NHID))[lane];
    float accx = w * hv.x, accy = w * hv.y, ssum = w;

    const int jb = offs[i];
    const int je = jb + cnt[i];
    for (int j = jb; j < je; ++j) {
        int sv = esrc[j];
        float a = asrc[sv] + adi;
        a = (a > 0.f) ? a : NEG_SLOPE * a;
        float ww = __expf(fminf(a, 60.f));
        float2 hs = ((const float2*)(h + (size_t)sv * NHID))[lane];
        accx += ww * hs.x;
        accy += ww * hs.y;
        ssum += ww;
    }

    float inv = 1.0f / (ssum + 1e-16f);
    float ox = accx * inv + bias[2 * lane];
    float oy = accy * inv + bias[2 * lane + 1];

    float l0 = ox * fcw[2 * lane] + oy * fcw[2 * lane + 1];
    float l1 = ox * fcw[NHID + 2 * lane] + oy * fcw[NHID + 2 * lane + 1];
#pragma unroll
    for (int off = 32; off > 0; off >>= 1) {
        l0 += __shfl_down(l0, off);
        l1 += __shfl_down(l1, off);
    }
    if (lane == 0) {
        l0 += fcb[0];
        l1 += fcb[1];
        float m = fmaxf(l0, l1);
        float ls = m + __logf(__expf(l0 - m) + __expf(l1 - m));
        ((float2*)out)[i] = make_float2(l0 - ls, l1 - ls);
    }
}

// ---------------------------------------------------------------------------
extern "C" void kernel_launch(void* const* d_in, const int* in_sizes, int n_in,
                              void* d_out, int out_size, void* d_ws, size_t ws_size,
                              hipStream_t stream)
{
    const float* x    = (const float*)d_in[0];  // f32 [100000,256]
    const int*   ei   = (const int*)d_in[1];    // int32 [2,1600000]
    const float* W    = (const float*)d_in[2];  // f32 [256,128]
    const float* atts = (const float*)d_in[3];  // f32 [128]
    const float* attd = (const float*)d_in[4];  // f32 [128]
    const float* bias = (const float*)d_in[5];  // f32 [128]
    const float* fcw  = (const float*)d_in[6];  // f32 [2,128]
    const float* fcb  = (const float*)d_in[7];  // f32 [2]
    float*       out  = (float*)d_out;          // f32 [100000,2]

    char* base = (char*)d_ws;
    size_t off = 0;
    auto carve = [&](size_t bytes) -> char* {
        char* p = base + off;
        off = (off + bytes + 255) & ~(size_t)255;
        return p;
    };
    float*          h      = (float*)carve((size_t)N_NODES * NHID * 4);  // 51.2 MB
    float*          asrc   = (float*)carve(N_NODES * 4);
    float*          adst   = (float*)carve(N_NODES * 4);
    int*            cnt    = (int*)carve(N_NODES * 4);
    int*            offs   = (int*)carve(N_NODES * 4);
    int*            cursor = (int*)carve(N_NODES * 4);
    int*            total  = (int*)carve(256);
    int*            esrc   = (int*)carve((size_t)N_EDGES * 4);
    unsigned short* Wt     = (unsigned short*)carve(NHID * NFEAT * 2);   // 64 KB
    (void)ws_size; (void)in_sizes; (void)n_in; (void)out_size;

    hipMemsetAsync(cnt, 0, N_NODES * 4, stream);
    hipMemsetAsync(cursor, 0, N_NODES * 4, stream);
    hipMemsetAsync(total, 0, 4, stream);

    const int GB = (N_NODES + 127) / 128;  // 782 blocks

    k_conv<<<(NHID * NFEAT) / 256, 256, 0, stream>>>(W, Wt);
    k_gemm_mfma<<<GB, 256, 0, stream>>>(x, Wt, h);
    k_att<<<(N_NODES + 3) / 4, 256, 0, stream>>>(h, atts, attd, asrc, adst);
    k_hist<<<(N_EDGES + 255) / 256, 256, 0, stream>>>(ei, cnt);
    k_alloc<<<(N_NODES + 255) / 256, 256, 0, stream>>>(cnt, offs, total);
    k_scatter<<<(N_EDGES + 255) / 256, 256, 0, stream>>>(ei, offs, cursor, esrc);
    k_agg<<<(N_NODES + 3) / 4, 256, 0, stream>>>(h, asrc, adst, offs, cnt, esrc,
                                                 bias, fcw, fcb, out);
}

// Round 5
// 456.372 us; speedup vs baseline: 2.0666x; 1.2156x over previous
//
#include <hip/hip_runtime.h>
#include <hip/hip_bf16.h>
#include <stdint.h>

// Problem constants (from reference)
#define N_NODES 100000
#define N_EDGES 1600000
#define NFEAT   256
#define NHID    128
#define NEG_SLOPE 0.2f

typedef __attribute__((ext_vector_type(8))) short short8;   // 8 bf16 (4 VGPRs)
typedef __attribute__((ext_vector_type(4))) float f32x4;    // MFMA C/D frag

__device__ __forceinline__ int clamp_node(int v) {
    unsigned u = (unsigned)v;
    return (u < (unsigned)N_NODES) ? (int)u : 0;
}

// fp32 -> bf16 (RNE). Exact when the fp32 value is already bf16-rounded.
__device__ __forceinline__ unsigned short f2bf(float f) {
    unsigned u = __float_as_uint(f);
    return (unsigned short)((u + 0x7fffu + ((u >> 16) & 1u)) >> 16);
}
__device__ __forceinline__ float bflo(unsigned p) { return __uint_as_float(p << 16); }
__device__ __forceinline__ float bfhi(unsigned p) { return __uint_as_float(p & 0xffff0000u); }

// ---------------------------------------------------------------------------
// K0: W [256,128] fp32 -> Wt [128,256] bf16 (n-major).
// ---------------------------------------------------------------------------
__global__ __launch_bounds__(256) void k_conv(
    const float* __restrict__ W, unsigned short* __restrict__ Wt)
{
    int id = blockIdx.x * 256 + threadIdx.x;  // n*256 + k
    int n = id >> 8, k = id & 255;
    Wt[id] = f2bf(W[k * NHID + n]);
}

// ---------------------------------------------------------------------------
// K1: h = x @ W via bf16 MFMA, fp32 accumulate; OUTPUT IS bf16 (hb).
// 128x128 tile, 4 waves (2x2), each 64x64 via 4x4 16x16x32 fragments.
// ---------------------------------------------------------------------------
#define LDS_STRIDE 40
__global__ __launch_bounds__(256) void k_gemm_mfma(
    const float* __restrict__ x,            // [N, 256] fp32 (bf16-valued)
    const unsigned short* __restrict__ Wt,  // [128, 256] bf16, n-major
    unsigned short* __restrict__ hb)        // [N, 128] bf16
{
    __shared__ unsigned short As[128 * LDS_STRIDE];
    __shared__ unsigned short Bs[128 * LDS_STRIDE];

    const int tid  = threadIdx.x;
    const int wave = tid >> 6;
    const int lane = tid & 63;
    const int wm = wave >> 1, wn = wave & 1;
    const int lr = lane & 15, q = lane >> 4;
    const int blockM = blockIdx.x * 128;

    const int sr = tid >> 1;   // staging row 0..127
    const int hh = tid & 1;    // staging half (16 elems)

    f32x4 acc[4][4];
#pragma unroll
    for (int a = 0; a < 4; ++a)
#pragma unroll
        for (int b = 0; b < 4; ++b) acc[a][b] = 0.f;

    const int growA = min(blockM + sr, N_NODES - 1);
    const float* xrow = x + (size_t)growA * NFEAT + hh * 16;
    const unsigned short* wrow = Wt + sr * NFEAT + hh * 16;

    for (int kt = 0; kt < 8; ++kt) {
        const float4* xp = (const float4*)(xrow + kt * 32);
        float4 v0 = xp[0], v1 = xp[1], v2 = xp[2], v3 = xp[3];
        short8 pa0, pa1;
        pa0[0] = f2bf(v0.x); pa0[1] = f2bf(v0.y); pa0[2] = f2bf(v0.z); pa0[3] = f2bf(v0.w);
        pa0[4] = f2bf(v1.x); pa0[5] = f2bf(v1.y); pa0[6] = f2bf(v1.z); pa0[7] = f2bf(v1.w);
        pa1[0] = f2bf(v2.x); pa1[1] = f2bf(v2.y); pa1[2] = f2bf(v2.z); pa1[3] = f2bf(v2.w);
        pa1[4] = f2bf(v3.x); pa1[5] = f2bf(v3.y); pa1[6] = f2bf(v3.z); pa1[7] = f2bf(v3.w);
        uint4 pb0 = *(const uint4*)(wrow + kt * 32);
        uint4 pb1 = *(const uint4*)(wrow + kt * 32 + 8);

        __syncthreads();
        *(short8*)&As[sr * LDS_STRIDE + hh * 16 + 0] = pa0;
        *(short8*)&As[sr * LDS_STRIDE + hh * 16 + 8] = pa1;
        *(uint4*)&Bs[sr * LDS_STRIDE + hh * 16 + 0] = pb0;
        *(uint4*)&Bs[sr * LDS_STRIDE + hh * 16 + 8] = pb1;
        __syncthreads();

        short8 af[4], bfr[4];
#pragma unroll
        for (int mt = 0; mt < 4; ++mt)
            af[mt] = *(const short8*)&As[(wm * 64 + mt * 16 + lr) * LDS_STRIDE + q * 8];
#pragma unroll
        for (int nt = 0; nt < 4; ++nt)
            bfr[nt] = *(const short8*)&Bs[(wn * 64 + nt * 16 + lr) * LDS_STRIDE + q * 8];

#pragma unroll
        for (int mt = 0; mt < 4; ++mt)
#pragma unroll
            for (int nt = 0; nt < 4; ++nt)
                acc[mt][nt] = __builtin_amdgcn_mfma_f32_16x16x32_bf16(
                    af[mt], bfr[nt], acc[mt][nt], 0, 0, 0);
    }

    // epilogue: C/D layout col=lane&15, row=quad*4+reg; store bf16
#pragma unroll
    for (int mt = 0; mt < 4; ++mt) {
#pragma unroll
        for (int reg = 0; reg < 4; ++reg) {
            int grow = blockM + wm * 64 + mt * 16 + q * 4 + reg;
            if (grow < N_NODES) {
                unsigned short* hp = hb + (size_t)grow * NHID + wn * 64 + lr;
#pragma unroll
                for (int nt = 0; nt < 4; ++nt)
                    hp[nt * 16] = f2bf(acc[mt][nt][reg]);
            }
        }
    }
}

// ---------------------------------------------------------------------------
// K2: attention scalars from bf16 h. One wave per node.
// ---------------------------------------------------------------------------
__global__ __launch_bounds__(256) void k_att(
    const unsigned short* __restrict__ hb,
    const float* __restrict__ atts,  // [128]
    const float* __restrict__ attd,  // [128]
    float* __restrict__ asrc,
    float* __restrict__ adst)
{
    const int wave = threadIdx.x >> 6;
    const int lane = threadIdx.x & 63;
    const int i = blockIdx.x * 4 + wave;
    if (i >= N_NODES) return;

    unsigned p = ((const unsigned*)(hb + (size_t)i * NHID))[lane];
    float hx = bflo(p), hy = bfhi(p);
    float ps = hx * atts[2 * lane] + hy * atts[2 * lane + 1];
    float pd = hx * attd[2 * lane] + hy * attd[2 * lane + 1];
#pragma unroll
    for (int off = 32; off > 0; off >>= 1) {
        ps += __shfl_down(ps, off);
        pd += __shfl_down(pd, off);
    }
    if (lane == 0) {
        asrc[i] = ps;
        adst[i] = pd;
    }
}

// ---------------------------------------------------------------------------
// CSR build (scan-free). Scatter also precomputes the per-edge softmax weight
// ew = exp(leaky(asrc[s]+adst[d])) so k_agg's inner loop has no dependent
// gather chain. meta[pos] = (src as float bits, ew).
// ---------------------------------------------------------------------------
__global__ void k_hist(const int* __restrict__ ei, int* __restrict__ cnt)
{
    int e = blockIdx.x * blockDim.x + threadIdx.x;
    if (e < N_EDGES) atomicAdd(&cnt[clamp_node(ei[N_EDGES + e])], 1);
}

__global__ void k_alloc(const int* __restrict__ cnt, int* __restrict__ offs,
                        int* __restrict__ total)
{
    int i = blockIdx.x * blockDim.x + threadIdx.x;
    if (i < N_NODES) offs[i] = atomicAdd(total, cnt[i]);
}

__global__ void k_scatter(const int* __restrict__ ei, const int* __restrict__ offs,
                          int* __restrict__ cursor,
                          const float* __restrict__ asrc,
                          const float* __restrict__ adst,
                          float2* __restrict__ meta)
{
    int e = blockIdx.x * blockDim.x + threadIdx.x;
    if (e < N_EDGES) {
        int d = clamp_node(ei[N_EDGES + e]);
        int s = clamp_node(ei[e]);
        float a = asrc[s] + adst[d];
        a = (a > 0.f) ? a : NEG_SLOPE * a;
        float ew = __expf(fminf(a, 60.f));
        int pos = offs[d] + atomicAdd(&cursor[d], 1);
        if ((unsigned)pos < (unsigned)N_EDGES)
            meta[pos] = make_float2(__int_as_float(s), ew);
    }
}

// ---------------------------------------------------------------------------
// K3: per-node aggregation + fused FC + log_softmax. One wave per node;
// lane holds cols {2l, 2l+1} (one uint = 2 bf16 per row). Edge loop unrolled
// x4: 4 independent 256B row-gathers in flight per wave.
// ---------------------------------------------------------------------------
__global__ __launch_bounds__(256) void k_agg(
    const unsigned short* __restrict__ hb, const float* __restrict__ asrc,
    const float* __restrict__ adst, const int* __restrict__ offs,
    const int* __restrict__ cnt, const float2* __restrict__ meta,
    const float* __restrict__ bias,  // [128]
    const float* __restrict__ fcw,   // [2,128]
    const float* __restrict__ fcb,   // [2]
    float* __restrict__ out)         // [N,2]
{
    const int wave = threadIdx.x >> 6;
    const int lane = threadIdx.x & 63;
    const int i = blockIdx.x * 4 + wave;
    if (i >= N_NODES) return;

    const unsigned* hrows = (const unsigned*)hb;  // row i at hrows[i*64]

    // self loop
    float e0 = asrc[i] + adst[i];
    e0 = (e0 > 0.f) ? e0 : NEG_SLOPE * e0;
    float w = __expf(fminf(e0, 60.f));
    unsigned pself = hrows[(size_t)i * 64 + lane];
    float accx = w * bflo(pself), accy = w * bfhi(pself), ssum = w;

    const float2* mp = meta + offs[i];
    const int n = cnt[i];
    int j = 0;
    for (; j + 4 <= n; j += 4) {
        float2 m0 = mp[j], m1 = mp[j + 1], m2 = mp[j + 2], m3 = mp[j + 3];
        unsigned p0 = hrows[(size_t)__float_as_int(m0.x) * 64 + lane];
        unsigned p1 = hrows[(size_t)__float_as_int(m1.x) * 64 + lane];
        unsigned p2 = hrows[(size_t)__float_as_int(m2.x) * 64 + lane];
        unsigned p3 = hrows[(size_t)__float_as_int(m3.x) * 64 + lane];
        accx += m0.y * bflo(p0); accy += m0.y * bfhi(p0);
        accx += m1.y * bflo(p1); accy += m1.y * bfhi(p1);
        accx += m2.y * bflo(p2); accy += m2.y * bfhi(p2);
        accx += m3.y * bflo(p3); accy += m3.y * bfhi(p3);
        ssum += m0.y + m1.y + m2.y + m3.y;
    }
    for (; j < n; ++j) {
        float2 m = mp[j];
        unsigned p = hrows[(size_t)__float_as_int(m.x) * 64 + lane];
        accx += m.y * bflo(p);
        accy += m.y * bfhi(p);
        ssum += m.y;
    }

    float inv = 1.0f / (ssum + 1e-16f);
    float ox = accx * inv + bias[2 * lane];
    float oy = accy * inv + bias[2 * lane + 1];

    float l0 = ox * fcw[2 * lane] + oy * fcw[2 * lane + 1];
    float l1 = ox * fcw[NHID + 2 * lane] + oy * fcw[NHID + 2 * lane + 1];
#pragma unroll
    for (int off = 32; off > 0; off >>= 1) {
        l0 += __shfl_down(l0, off);
        l1 += __shfl_down(l1, off);
    }
    if (lane == 0) {
        l0 += fcb[0];
        l1 += fcb[1];
        float m = fmaxf(l0, l1);
        float ls = m + __logf(__expf(l0 - m) + __expf(l1 - m));
        ((float2*)out)[i] = make_float2(l0 - ls, l1 - ls);
    }
}

// ---------------------------------------------------------------------------
extern "C" void kernel_launch(void* const* d_in, const int* in_sizes, int n_in,
                              void* d_out, int out_size, void* d_ws, size_t ws_size,
                              hipStream_t stream)
{
    const float* x    = (const float*)d_in[0];
    const int*   ei   = (const int*)d_in[1];
    const float* W    = (const float*)d_in[2];
    const float* atts = (const float*)d_in[3];
    const float* attd = (const float*)d_in[4];
    const float* bias = (const float*)d_in[5];
    const float* fcw  = (const float*)d_in[6];
    const float* fcb  = (const float*)d_in[7];
    float*       out  = (float*)d_out;

    char* base = (char*)d_ws;
    size_t off = 0;
    auto carve = [&](size_t bytes) -> char* {
        char* p = base + off;
        off = (off + bytes + 255) & ~(size_t)255;
        return p;
    };
    unsigned short* hb     = (unsigned short*)carve((size_t)N_NODES * NHID * 2);  // 25.6 MB
    float*          asrc   = (float*)carve(N_NODES * 4);
    float*          adst   = (float*)carve(N_NODES * 4);
    int*            cnt    = (int*)carve(N_NODES * 4);
    int*            offs   = (int*)carve(N_NODES * 4);
    int*            cursor = (int*)carve(N_NODES * 4);
    int*            total  = (int*)carve(256);
    float2*         meta   = (float2*)carve((size_t)N_EDGES * 8);                 // 12.8 MB
    unsigned short* Wt     = (unsigned short*)carve(NHID * NFEAT * 2);            // 64 KB
    (void)ws_size; (void)in_sizes; (void)n_in; (void)out_size;

    hipMemsetAsync(cnt, 0, N_NODES * 4, stream);
    hipMemsetAsync(cursor, 0, N_NODES * 4, stream);
    hipMemsetAsync(total, 0, 4, stream);

    const int GB = (N_NODES + 127) / 128;

    k_conv<<<(NHID * NFEAT) / 256, 256, 0, stream>>>(W, Wt);
    k_gemm_mfma<<<GB, 256, 0, stream>>>(x, Wt, hb);
    k_att<<<(N_NODES + 3) / 4, 256, 0, stream>>>(hb, atts, attd, asrc, adst);
    k_hist<<<(N_EDGES + 255) / 256, 256, 0, stream>>>(ei, cnt);
    k_alloc<<<(N_NODES + 255) / 256, 256, 0, stream>>>(cnt, offs, total);
    k_scatter<<<(N_EDGES + 255) / 256, 256, 0, stream>>>(ei, offs, cursor,
                                                         asrc, adst, meta);
    k_agg<<<(N_NODES + 3) / 4, 256, 0, stream>>>(hb, asrc, adst, offs, cnt, meta,
                                                 bias, fcw, fcb, out);
}